// Round 1
// baseline (3596.096 us; speedup 1.0000x reference)
//
#include <hip/hip_runtime.h>
#include <math.h>

#define B_ 2
#define V_ 8
#define C_ 64
#define HW_ 16384      // H*W
#define A_ 256
#define P_ 65536       // A*A
#define C3_ 194
#define CO_ 192
#define CPG_ 24
#define NG_ 8

// workspace layout (bytes)
#define OFF_CTX   0ull
#define SZ_CTX    (2ull*194*65536*4)          // 101,711,872
#define OFF_ACC   (OFF_CTX + SZ_CTX)
#define SZ_ACC    (2ull*65536*192*4)          // 100,663,296
#define OFF_CNT   (OFF_ACC + SZ_ACC)
#define SZ_CNT    (2ull*3*65536*4)            // 1,572,864
#define OFF_H2    OFF_ACC                     // overlay (acc dead after finalize)
#define OFF_H1    (OFF_CNT + SZ_CNT)
#define SZ_H1     (2ull*192*65536*4)
#define OFF_SMALL (OFF_H1 + SZ_H1)

// d_out offsets (floats)
#define OUT_B   8388608
#define OUT_COV 25165824
#define OUT_UNC 25296896
#define OUT_CONF 25427968

__device__ __forceinline__ float sigmoidf_(float x){ return 1.f/(1.f+expf(-x)); }

// ---------------- K1: fused tri-branch scatter ----------------
__global__ __launch_bounds__(256) void k_fuse(const float* __restrict__ vf,
    const float* __restrict__ uvs, const float* __restrict__ masks,
    const float* __restrict__ wgp, const float* __restrict__ wbp, const float* __restrict__ whp,
    float* __restrict__ acc, float* __restrict__ cnt)
{
  __shared__ __align__(16) float sf[64*65];
  __shared__ int sidx[64];
  __shared__ int svalid[64];
  __shared__ float sw[3];
  int t = threadIdx.x;
  int pix0 = blockIdx.x*64;
  int b   = pix0 / (V_*HW_);
  int rem = pix0 % (V_*HW_);
  int v   = rem / HW_;
  int p2  = rem % HW_;
  size_t vbase = ((size_t)(b*V_+v))*C_*HW_;
  for (int i=0;i<16;i++){
    int f = t + i*256;
    int c = f>>6, px = f&63;
    sf[c*65+px] = vf[vbase + (size_t)c*HW_ + p2 + px];
  }
  if (t<64){
    const float* u2 = uvs + (((size_t)(b*V_+v))*HW_ + p2 + t)*2;
    float ux = u2[0], uy = u2[1];
    int fin = isfinite(ux) && isfinite(uy);
    float su = fin?ux:0.f, svv = fin?uy:0.f;
    float cu = fminf(fmaxf(su,0.f),1.f);
    float cv = fminf(fmaxf(svv,0.f),1.f);
    int xi = (int)rintf(cu*255.f);
    int yi = (int)rintf((1.f-cv)*255.f);
    sidx[t] = yi*256+xi;
    float m = masks[((size_t)(b*V_+v))*HW_ + p2 + t];
    svalid[t] = (m>0.5f) && fin;
  }
  if (t<3){
    const float* wp = (t==0)?wgp:((t==1)?wbp:whp);
    sw[t] = fmaxf(wp[b*V_+v], 0.f);
  }
  __syncthreads();
  int wave = t>>6, lane = t&63;
  float w0 = sw[0], w1 = sw[1], w2 = sw[2];
  for (int i=0;i<16;i++){
    int px = wave*16+i;
    if (!svalid[px]) continue;         // wave-uniform
    int bin = sidx[px];
    float val = sf[lane*65+px];
    size_t base = ((size_t)b*P_ + bin)*192;
    if (w0>0.f) atomicAdd(&acc[base + lane],        val*w0);
    if (w1>0.f) atomicAdd(&acc[base + 64 + lane],   val*w1);
    if (w2>0.f) atomicAdd(&acc[base + 128 + lane],  val*w2);
    if (lane<3){
      float wv = sw[lane];
      if (wv>0.f) atomicAdd(&cnt[((size_t)(b*3+lane))*P_ + bin], wv);
    }
  }
}

// ---------------- K2: finalize atlases -> ctx, coverage, raw uncertainty ----------------
__global__ __launch_bounds__(256) void k_finalize(const float* __restrict__ acc,
      const float* __restrict__ cnt, float* __restrict__ ctx,
      float* __restrict__ out_cov, int* __restrict__ scale)
{
  __shared__ __align__(16) float sv[64*193];
  __shared__ float sc[3][64];
  __shared__ float up[256];
  int t = threadIdx.x;
  int bin0 = blockIdx.x*64;
  int b = bin0 >> 16;
  int p0 = bin0 & 65535;
  size_t abase = ((size_t)b*P_ + p0)*192;
  for (int i=0;i<48;i++){
    int f = t + i*256;
    int bl = f/192, c = f - bl*192;
    sv[bl*193+c] = acc[abase + f];
  }
  if (t<192){
    int br = t>>6, bl = t&63;
    sc[br][bl] = cnt[((size_t)(b*3+br))*P_ + p0 + bl];
  }
  __syncthreads();
  {
    int bl = t>>2, q = t&3;
    float dg = 1.f/fmaxf(sc[0][bl],1.f);
    float db = 1.f/fmaxf(sc[1][bl],1.f);
    float dh = 1.f/fmaxf(sc[2][bl],1.f);
    float s = 0.f;
    for (int j=0;j<16;j++){
      int c = q*16+j;
      float fg = sv[bl*193+c]*dg;
      float fb = sv[bl*193+64+c]*db;
      float fh = sv[bl*193+128+c]*dh;
      sv[bl*193+c]=fg; sv[bl*193+64+c]=fb; sv[bl*193+128+c]=fh;
      float m = (fg+fb+fh)*(1.f/3.f);
      float d0=fg-m, d1=fb-m, d2=fh-m;
      s += d0*d0+d1*d1+d2*d2;
    }
    up[t] = s;
  }
  __syncthreads();
  if (t<64){
    float tot = up[t*4]+up[t*4+1]+up[t*4+2]+up[t*4+3];
    float u = sqrtf(tot*(1.f/192.f));           // mean over 64 ch of (ss/3)
    float vg = sc[0][t]>0.f?1.f:0.f;
    float vb = sc[1][t]>0.f?1.f:0.f;
    float vh = sc[2][t]>0.f?1.f:0.f;
    float cov = fminf(fmaxf((vg+vb+vh)*(1.f/3.f),0.f),1.f);
    ctx[((size_t)b*194+192)*P_ + p0 + t] = cov;
    ctx[((size_t)b*194+193)*P_ + p0 + t] = u;
    out_cov[(size_t)b*P_ + p0 + t] = cov;
    atomicMax(&scale[b], __float_as_int(u));    // u >= 0: int order == float order
  }
  __syncthreads();
  {
    int bl = t&63, cg = t>>6;
    for (int j=0;j<48;j++){
      int c = cg*48+j;
      ctx[((size_t)b*194+c)*P_ + p0 + bl] = sv[bl*193+c];
    }
  }
}

// ---------------- K3: normalize uncertainty ----------------
__global__ __launch_bounds__(256) void k_norm_unc(float* __restrict__ ctx,
    const int* __restrict__ scale, float* __restrict__ out_unc)
{
  int tid = blockIdx.x*256 + threadIdx.x;
  int b = tid >> 16, p = tid & 65535;
  float s = fmaxf(__int_as_float(scale[b]), 1e-6f);
  float u   = ctx[((size_t)b*194+193)*P_ + p];
  float cov = ctx[((size_t)b*194+192)*P_ + p];
  float un = fminf(fmaxf(u/s,0.f),1.f)*cov;
  ctx[((size_t)b*194+193)*P_ + p] = un;
  out_unc[(size_t)b*P_ + p] = un;
}

// ---------------- conv 3x3 'SAME', direct, LDS tiled ----------------
// block: 256 thr = 4(x-groups of 8px) x 8(y) x 8(oc-groups of 4)
// tile: 32x8 spatial, 32 oc; IC chunked by 16
template<int IC>
__global__ __launch_bounds__(256) void k_conv3(const float* __restrict__ in,
    const float* __restrict__ wgt, const float* __restrict__ bias, float* __restrict__ out)
{
  __shared__ __align__(16) float s_in[16*10*36];
  __shared__ __align__(16) float s_w[16*9*32];
  int t = threadIdx.x;
  int b = blockIdx.z/6, ocb = blockIdx.z%6;
  int oc0 = ocb*32;
  int tx = t&3, ty = (t>>2)&7, tg = t>>5;
  int x0 = blockIdx.x*32, y0 = blockIdx.y*8;
  float acc[8][4];
  #pragma unroll
  for (int j=0;j<4;j++){
    float bv = bias[oc0+tg*4+j];
    #pragma unroll
    for (int px=0;px<8;px++) acc[px][j]=bv;
  }
  const int nchunk = (IC+15)/16;
  for (int chk=0; chk<nchunk; chk++){
    int ic0 = chk*16;
    __syncthreads();
    for (int f=t; f<5760; f+=256){
      int xx = f%36, yy = (f/36)%10, icl = f/360;
      int ic = ic0+icl;
      float vv = 0.f;
      if (xx<34 && ic<IC){
        int gx = x0+xx-1, gy = y0+yy-1;
        if (gx>=0 && gx<256 && gy>=0 && gy<256)
          vv = in[((size_t)b*IC + ic)*P_ + gy*256 + gx];
      }
      s_in[f]=vv;
    }
    for (int f=t; f<4608; f+=256){
      int ocl = f&31, k = (f>>5)%9, icl = f/288;
      int ic = ic0+icl;
      s_w[f] = (ic<IC) ? wgt[((size_t)(oc0+ocl)*IC + ic)*9 + k] : 0.f;
    }
    __syncthreads();
    #pragma unroll 1
    for (int icl=0; icl<16; icl++){
      #pragma unroll
      for (int ky=0; ky<3; ky++){
        int rb = (icl*10 + ty + ky)*36 + tx*8;
        float4 a0 = *(const float4*)&s_in[rb];
        float4 a1 = *(const float4*)&s_in[rb+4];
        float4 a2 = *(const float4*)&s_in[rb+8];
        float av[12] = {a0.x,a0.y,a0.z,a0.w,a1.x,a1.y,a1.z,a1.w,a2.x,a2.y,a2.z,a2.w};
        #pragma unroll
        for (int kx=0; kx<3; kx++){
          float4 wv = *(const float4*)&s_w[(icl*9 + ky*3 + kx)*32 + tg*4];
          #pragma unroll
          for (int px=0;px<8;px++){
            float xv = av[kx+px];
            acc[px][0] = fmaf(xv, wv.x, acc[px][0]);
            acc[px][1] = fmaf(xv, wv.y, acc[px][1]);
            acc[px][2] = fmaf(xv, wv.z, acc[px][2]);
            acc[px][3] = fmaf(xv, wv.w, acc[px][3]);
          }
        }
      }
    }
  }
  #pragma unroll
  for (int j=0;j<4;j++){
    int oc = oc0+tg*4+j;
    size_t ob = ((size_t)b*CO_ + oc)*P_ + (y0+ty)*256 + x0 + tx*8;
    *(float4*)&out[ob]   = make_float4(acc[0][j],acc[1][j],acc[2][j],acc[3][j]);
    *(float4*)&out[ob+4] = make_float4(acc[4][j],acc[5][j],acc[6][j],acc[7][j]);
  }
}

// ---------------- group-norm stats (double atomics) ----------------
__global__ __launch_bounds__(256) void k_gn_stats(const float* __restrict__ x, double* __restrict__ stats)
{
  int bg = blockIdx.x;
  size_t base = (size_t)bg*CPG_*P_ + (size_t)blockIdx.y*32768;
  int t = threadIdx.x;
  double s1=0.0, s2=0.0;
  for (int i=t; i<32768; i+=256){
    float vv = x[base+i];
    s1 += vv; s2 += (double)vv*(double)vv;
  }
  for (int off=32; off>0; off>>=1){
    s1 += __shfl_down(s1, off, 64);
    s2 += __shfl_down(s2, off, 64);
  }
  __shared__ double ls[8];
  int lane = t&63, w = t>>6;
  if (lane==0){ ls[w*2]=s1; ls[w*2+1]=s2; }
  __syncthreads();
  if (t==0){
    atomicAdd(&stats[bg*2],   ls[0]+ls[2]+ls[4]+ls[6]);
    atomicAdd(&stats[bg*2+1], ls[1]+ls[3]+ls[5]+ls[7]);
  }
}

// ---------------- group-norm apply + SiLU, in place ----------------
__global__ __launch_bounds__(256) void k_gn_apply(float* __restrict__ x, const double* __restrict__ stats,
    const float* __restrict__ gs, const float* __restrict__ gb)
{
  int idx = blockIdx.x*256 + threadIdx.x;   // float4 index, total 6,291,456
  int flat = idx*4;
  int b = flat / (CO_*P_);
  int c = (flat - b*CO_*P_) >> 16;
  int bg = b*NG_ + c/CPG_;
  const double N = (double)(CPG_*P_);
  double mu = stats[bg*2]/N;
  double var = stats[bg*2+1]/N - mu*mu;
  float rstd = 1.0f/sqrtf((float)var + 1e-5f);
  float mean = (float)mu;
  float sc = gs[c], bi = gb[c];
  float4 vv = *(float4*)&x[(size_t)flat];
  float o[4] = {vv.x,vv.y,vv.z,vv.w};
  #pragma unroll
  for (int i=0;i<4;i++){
    float xn = (o[i]-mean)*rstd*sc + bi;
    o[i] = xn*sigmoidf_(xn);
  }
  *(float4*)&x[(size_t)flat] = make_float4(o[0],o[1],o[2],o[3]);
}

// ---------------- global average pool per (b,c) ----------------
__global__ __launch_bounds__(256) void k_pool(const float* __restrict__ x, float* __restrict__ pooled)
{
  int bc = blockIdx.x;
  size_t base = (size_t)bc*P_;
  int t = threadIdx.x;
  double s=0.0;
  for (int i=t; i<P_; i+=256) s += x[base+i];
  for (int off=32; off>0; off>>=1) s += __shfl_down(s, off, 64);
  __shared__ double ls[4];
  int lane = t&63, w = t>>6;
  if (lane==0) ls[w]=s;
  __syncthreads();
  if (t==0) pooled[bc] = (float)((ls[0]+ls[1]+ls[2]+ls[3]) / (double)P_);
}

// ---------------- channel gate MLP ----------------
__global__ void k_gate(const float* __restrict__ pooled, const float* __restrict__ gw1,
    const float* __restrict__ gb1, const float* __restrict__ gw2, const float* __restrict__ gb2,
    float* __restrict__ gatef)
{
  __shared__ float hb[2*48];
  int t = threadIdx.x;
  if (t<96){
    int b=t/48, j=t%48;
    float a = gb1[j];
    for (int c=0;c<192;c++) a = fmaf(pooled[b*192+c], gw1[j*192+c], a);
    hb[t] = a*sigmoidf_(a);
  }
  __syncthreads();
  for (int i=t;i<384;i+=256){
    int b=i/192, c=i%192;
    float a = gb2[c];
    for (int j=0;j<48;j++) a = fmaf(hb[b*48+j], gw2[c*48+j], a);
    gatef[i] = 0.5f + sigmoidf_(a);
  }
}

// ---------------- confidence head ----------------
__global__ __launch_bounds__(256) void k_conf(const float* __restrict__ ctx,
    const float* __restrict__ cw, const float* __restrict__ cb, float* __restrict__ out_conf)
{
  int p = blockIdx.x*256 + threadIdx.x;
  int b = blockIdx.y;
  float a0=cb[0], a1=cb[1], a2=cb[2];
  const float* cp = ctx + (size_t)b*194*P_ + p;
  for (int c=0;c<194;c++){
    float xv = cp[(size_t)c*P_];
    a0 = fmaf(xv, cw[c],     a0);
    a1 = fmaf(xv, cw[194+c], a1);
    a2 = fmaf(xv, cw[388+c], a2);
  }
  out_conf[((size_t)(b*3+0))*P_ + p] = sigmoidf_(a0);
  out_conf[((size_t)(b*3+1))*P_ + p] = sigmoidf_(a1);
  out_conf[((size_t)(b*3+2))*P_ + p] = sigmoidf_(a2);
}

// ---------------- 1x1 residual GEMM + final mix ----------------
__global__ __launch_bounds__(256) void k_combine(const float* __restrict__ ctx,
    const float* __restrict__ h2, const float* __restrict__ rpw, const float* __restrict__ rpb,
    const float* __restrict__ gatef, const float* __restrict__ conf_out,
    const float* __restrict__ rs, const float* __restrict__ mix, float* __restrict__ dout)
{
  __shared__ __align__(16) float s_x[16*256];
  __shared__ __align__(16) float s_w[16*32];
  int t = threadIdx.x;
  int p0 = blockIdx.x*256;
  int oc0 = blockIdx.y*32;
  int b = blockIdx.z;
  int pxt = t&31, tg = t>>5;
  float acc[8][4];
  #pragma unroll
  for (int j=0;j<4;j++){
    float bv = rpb[oc0+tg*4+j];
    #pragma unroll
    for (int px=0;px<8;px++) acc[px][j]=bv;
  }
  for (int chk=0; chk<13; chk++){
    int c0 = chk*16;
    __syncthreads();
    for (int f=t; f<4096; f+=256){
      int cl=f>>8, px=f&255;
      int c=c0+cl;
      s_x[f] = (c<194)? ctx[((size_t)b*194+c)*P_ + p0+px] : 0.f;
    }
    for (int f=t; f<512; f+=256){
      int cl=f>>5, ocl=f&31;
      int c=c0+cl;
      s_w[f] = (c<194)? rpw[(size_t)(oc0+ocl)*194 + c] : 0.f;
    }
    __syncthreads();
    #pragma unroll 1
    for (int cl=0; cl<16; cl++){
      float4 x0 = *(const float4*)&s_x[cl*256 + pxt*8];
      float4 x1 = *(const float4*)&s_x[cl*256 + pxt*8 + 4];
      float4 wv = *(const float4*)&s_w[cl*32 + tg*4];
      float xv[8] = {x0.x,x0.y,x0.z,x0.w,x1.x,x1.y,x1.z,x1.w};
      #pragma unroll
      for (int px=0;px<8;px++){
        acc[px][0]=fmaf(xv[px],wv.x,acc[px][0]);
        acc[px][1]=fmaf(xv[px],wv.y,acc[px][1]);
        acc[px][2]=fmaf(xv[px],wv.z,acc[px][2]);
        acc[px][3]=fmaf(xv[px],wv.w,acc[px][3]);
      }
    }
  }
  float trs = tanhf(rs[0]);
  float ms  = tanhf(mix[0]);
  int br = (oc0+tg*4)>>6;   // same for all 4 ocs of this thread
  float cf[8];
  {
    size_t cbase = ((size_t)(b*3+br))*P_ + p0 + pxt*8;
    float4 c0v = *(const float4*)&conf_out[cbase];
    float4 c1v = *(const float4*)&conf_out[cbase+4];
    cf[0]=c0v.x; cf[1]=c0v.y; cf[2]=c0v.z; cf[3]=c0v.w;
    cf[4]=c1v.x; cf[5]=c1v.y; cf[6]=c1v.z; cf[7]=c1v.w;
  }
  #pragma unroll
  for (int j=0;j<4;j++){
    int oc = oc0+tg*4+j;
    int cc = oc&63;
    float gv = gatef[b*192+oc];
    size_t src  = ((size_t)b*194+oc)*P_ + p0 + pxt*8;
    size_t hsrc = ((size_t)b*192+oc)*P_ + p0 + pxt*8;
    float4 f0 = *(const float4*)&ctx[src];
    float4 f1 = *(const float4*)&ctx[src+4];
    float4 h0 = *(const float4*)&h2[hsrc];
    float4 h1v= *(const float4*)&h2[hsrc+4];
    float fv[8]={f0.x,f0.y,f0.z,f0.w,f1.x,f1.y,f1.z,f1.w};
    float hv[8]={h0.x,h0.y,h0.z,h0.w,h1v.x,h1v.y,h1v.z,h1v.w};
    float ov[8];
    #pragma unroll
    for (int px=0;px<8;px++)
      ov[px] = fv[px] + ms * (hv[px]*gv + trs*acc[px][j]) * cf[px];
    size_t dst = (size_t)br*OUT_B + ((size_t)b*64+cc)*P_ + p0 + pxt*8;
    *(float4*)&dout[dst]   = make_float4(ov[0],ov[1],ov[2],ov[3]);
    *(float4*)&dout[dst+4] = make_float4(ov[4],ov[5],ov[6],ov[7]);
  }
}

extern "C" void kernel_launch(void* const* d_in, const int* in_sizes, int n_in,
                              void* d_out, int out_size, void* d_ws, size_t ws_size,
                              hipStream_t stream)
{
  const float* vf    = (const float*)d_in[0];
  const float* uvs   = (const float*)d_in[1];
  const float* masks = (const float*)d_in[2];
  const float* wg    = (const float*)d_in[3];
  const float* wb    = (const float*)d_in[4];
  const float* wh    = (const float*)d_in[5];
  // d_in[6] = atlas_size (256, hardcoded)
  const float* c1w = (const float*)d_in[7];
  const float* c1b = (const float*)d_in[8];
  const float* g1s = (const float*)d_in[9];
  const float* g1b = (const float*)d_in[10];
  const float* c2w = (const float*)d_in[11];
  const float* c2b = (const float*)d_in[12];
  const float* g2s = (const float*)d_in[13];
  const float* g2b = (const float*)d_in[14];
  const float* gw1 = (const float*)d_in[15];
  const float* gb1 = (const float*)d_in[16];
  const float* gw2 = (const float*)d_in[17];
  const float* gb2 = (const float*)d_in[18];
  const float* rpw = (const float*)d_in[19];
  const float* rpb = (const float*)d_in[20];
  const float* rs  = (const float*)d_in[21];
  const float* cw  = (const float*)d_in[22];
  const float* cb  = (const float*)d_in[23];
  const float* mix = (const float*)d_in[24];

  char* ws = (char*)d_ws;
  float*  ctx    = (float*)(ws + OFF_CTX);
  float*  accb   = (float*)(ws + OFF_ACC);
  float*  cntb   = (float*)(ws + OFF_CNT);
  float*  h1     = (float*)(ws + OFF_H1);
  float*  h2     = (float*)(ws + OFF_H2);
  double* stats1 = (double*)(ws + OFF_SMALL);
  double* stats2 = (double*)(ws + OFF_SMALL + 256);
  float*  pooled = (float*)(ws + OFF_SMALL + 512);
  float*  gatef  = (float*)(ws + OFF_SMALL + 2048);
  int*    scale  = (int*)(ws + OFF_SMALL + 3584);

  float* out = (float*)d_out;
  float* out_cov  = out + OUT_COV;
  float* out_unc  = out + OUT_UNC;
  float* out_conf = out + OUT_CONF;

  hipMemsetAsync(ws + OFF_ACC, 0, SZ_ACC + SZ_CNT, stream);
  hipMemsetAsync(ws + OFF_SMALL, 0, 4096, stream);

  k_fuse<<<4096, 256, 0, stream>>>(vf, uvs, masks, wg, wb, wh, accb, cntb);
  k_finalize<<<2048, 256, 0, stream>>>(accb, cntb, ctx, out_cov, scale);
  k_norm_unc<<<512, 256, 0, stream>>>(ctx, scale, out_unc);
  k_conv3<194><<<dim3(8,32,12), 256, 0, stream>>>(ctx, c1w, c1b, h1);
  k_gn_stats<<<dim3(16,48), 256, 0, stream>>>(h1, stats1);
  k_gn_apply<<<24576, 256, 0, stream>>>(h1, stats1, g1s, g1b);
  k_conv3<192><<<dim3(8,32,12), 256, 0, stream>>>(h1, c2w, c2b, h2);
  k_gn_stats<<<dim3(16,48), 256, 0, stream>>>(h2, stats2);
  k_gn_apply<<<24576, 256, 0, stream>>>(h2, stats2, g2s, g2b);
  k_pool<<<384, 256, 0, stream>>>(h2, pooled);
  k_gate<<<1, 256, 0, stream>>>(pooled, gw1, gb1, gw2, gb2, gatef);
  k_conf<<<dim3(256,2), 256, 0, stream>>>(ctx, cw, cb, out_conf);
  k_combine<<<dim3(256,6,2), 256, 0, stream>>>(ctx, h2, rpw, rpb, gatef, out_conf, rs, mix, out);
}

// Round 2
// 1259.005 us; speedup vs baseline: 2.8563x; 2.8563x over previous
//
#include <hip/hip_runtime.h>
#include <math.h>

#define B_ 2
#define V_ 8
#define C_ 64
#define HW_ 16384
#define A_ 256
#define P_ 65536
#define CO_ 192
#define CPG_ 24
#define NG_ 8
#define ICP1 224
#define ICP2 192

// workspace layout (bytes)
#define OFF_ACC   0ull
#define SZ_ACC    (2ull*65536*192*4)          // 100,663,296 ; reused for h1raw then h2
#define OFF_CNT   (OFF_ACC + SZ_ACC)
#define SZ_CNT    (2ull*3*65536*4)
#define OFF_CTXB  (OFF_CNT + SZ_CNT)          // ctx NHWC bf16, 224-ch padded
#define SZ_CTXB   (2ull*65536*224*2)
#define OFF_H1A   (OFF_CTXB + SZ_CTXB)        // h1 activated, NHWC bf16, 192 ch
#define SZ_H1A    (2ull*65536*192*2)
#define OFF_W1    (OFF_H1A + SZ_H1A)
#define SZ_W1     (9ull*192*224*2)
#define OFF_W2    (OFF_W1 + SZ_W1)
#define SZ_W2     (9ull*192*192*2)
#define OFF_SM    (OFF_W2 + SZ_W2 + 256)

// small-region offsets (within OFF_SM)
#define SM_STATS1 0
#define SM_STATS2 256
#define SM_SCALE  512
#define SM_POOLED 1024
#define SM_GATE   2560
#define SM_RAWU   8192

// d_out offsets (floats)
#define OUT_B    8388608
#define OUT_COV  25165824
#define OUT_UNC  25296896
#define OUT_CONF 25427968

typedef __attribute__((ext_vector_type(4))) float f32x4;
typedef __attribute__((ext_vector_type(8))) short bf16x8;

__device__ __forceinline__ float sigmoidf_(float x){ return 1.f/(1.f+expf(-x)); }
__device__ __forceinline__ float bf2f(unsigned short h){ return __uint_as_float(((unsigned)h)<<16); }
__device__ __forceinline__ unsigned short f2bf(float f){
  unsigned u = __float_as_uint(f);
  return (unsigned short)((u + 0x7fffu + ((u>>16)&1u)) >> 16);
}

// ---------------- K0: weight prep (transpose+pad+bf16) ----------------
__global__ __launch_bounds__(256) void k_prep(const float* __restrict__ c1w,
    const float* __restrict__ c2w, unsigned short* __restrict__ w1p, unsigned short* __restrict__ w2p)
{
  int idx = blockIdx.x*256 + threadIdx.x;
  const int N1 = 9*192*224;
  if (idx < N1){
    int ic = idx % 224; int oc = (idx/224) % 192; int k = idx/(224*192);
    float v = (ic < 194) ? c1w[(size_t)(oc*194+ic)*9 + k] : 0.f;
    w1p[idx] = f2bf(v);
  } else {
    int i2 = idx - N1;
    if (i2 < 9*192*192){
      int ic = i2 % 192; int oc = (i2/192) % 192; int k = i2/(192*192);
      w2p[i2] = f2bf(c2w[(size_t)(oc*192+ic)*9 + k]);
    }
  }
}

// ---------------- K1: fused tri-branch scatter ----------------
__global__ __launch_bounds__(256) void k_fuse(const float* __restrict__ vf,
    const float* __restrict__ uvs, const float* __restrict__ masks,
    const float* __restrict__ wgp, const float* __restrict__ wbp, const float* __restrict__ whp,
    float* __restrict__ acc, float* __restrict__ cnt)
{
  __shared__ __align__(16) float sf[64*65];
  __shared__ int sidx[64];
  __shared__ int svalid[64];
  __shared__ float sw[3];
  int t = threadIdx.x;
  int pix0 = blockIdx.x*64;
  int b   = pix0 / (V_*HW_);
  int rem = pix0 % (V_*HW_);
  int v   = rem / HW_;
  int p2  = rem % HW_;
  size_t vbase = ((size_t)(b*V_+v))*C_*HW_;
  for (int i=0;i<16;i++){
    int f = t + i*256;
    int c = f>>6, px = f&63;
    sf[c*65+px] = vf[vbase + (size_t)c*HW_ + p2 + px];
  }
  if (t<64){
    const float* u2 = uvs + (((size_t)(b*V_+v))*HW_ + p2 + t)*2;
    float ux = u2[0], uy = u2[1];
    int fin = isfinite(ux) && isfinite(uy);
    float su = fin?ux:0.f, svv = fin?uy:0.f;
    float cu = fminf(fmaxf(su,0.f),1.f);
    float cv = fminf(fmaxf(svv,0.f),1.f);
    int xi = (int)rintf(cu*255.f);
    int yi = (int)rintf((1.f-cv)*255.f);
    sidx[t] = yi*256+xi;
    float m = masks[((size_t)(b*V_+v))*HW_ + p2 + t];
    svalid[t] = (m>0.5f) && fin;
  }
  if (t<3){
    const float* wp = (t==0)?wgp:((t==1)?wbp:whp);
    sw[t] = fmaxf(wp[b*V_+v], 0.f);
  }
  __syncthreads();
  int wave = t>>6, lane = t&63;
  float w0 = sw[0], w1 = sw[1], w2 = sw[2];
  for (int i=0;i<16;i++){
    int px = wave*16+i;
    if (!svalid[px]) continue;
    int bin = sidx[px];
    float val = sf[lane*65+px];
    size_t base = ((size_t)b*P_ + bin)*192;
    if (w0>0.f) atomicAdd(&acc[base + lane],        val*w0);
    if (w1>0.f) atomicAdd(&acc[base + 64 + lane],   val*w1);
    if (w2>0.f) atomicAdd(&acc[base + 128 + lane],  val*w2);
    if (lane<3){
      float wv = sw[lane];
      if (wv>0.f) atomicAdd(&cnt[((size_t)(b*3+lane))*P_ + bin], wv);
    }
  }
}

// ---------------- K2: finalize atlases -> ctx bf16 NHWC, coverage, raw unc ----------------
__global__ __launch_bounds__(256) void k_finalize(const float* __restrict__ acc,
      const float* __restrict__ cnt, unsigned short* __restrict__ ctxb,
      float* __restrict__ out_cov, float* __restrict__ raw_unc, int* __restrict__ scale)
{
  __shared__ __align__(16) float sv[64*193];
  __shared__ float sc[3][64];
  __shared__ float up[256];
  __shared__ float s_cov[64];
  __shared__ float s_unc[64];
  int t = threadIdx.x;
  int bin0 = blockIdx.x*64;
  int b = bin0 >> 16;
  int p0 = bin0 & 65535;
  size_t abase = ((size_t)b*P_ + p0)*192;
  for (int i=0;i<48;i++){
    int f = t + i*256;
    int bl = f/192, c = f - bl*192;
    sv[bl*193+c] = acc[abase + f];
  }
  if (t<192){
    int br = t>>6, bl = t&63;
    sc[br][bl] = cnt[((size_t)(b*3+br))*P_ + p0 + bl];
  }
  __syncthreads();
  {
    int bl = t>>2, q = t&3;
    float dg = 1.f/fmaxf(sc[0][bl],1.f);
    float db = 1.f/fmaxf(sc[1][bl],1.f);
    float dh = 1.f/fmaxf(sc[2][bl],1.f);
    float s = 0.f;
    for (int j=0;j<16;j++){
      int c = q*16+j;
      float fg = sv[bl*193+c]*dg;
      float fb = sv[bl*193+64+c]*db;
      float fh = sv[bl*193+128+c]*dh;
      sv[bl*193+c]=fg; sv[bl*193+64+c]=fb; sv[bl*193+128+c]=fh;
      float m = (fg+fb+fh)*(1.f/3.f);
      float d0=fg-m, d1=fb-m, d2=fh-m;
      s += d0*d0+d1*d1+d2*d2;
    }
    up[t] = s;
  }
  __syncthreads();
  if (t<64){
    float tot = up[t*4]+up[t*4+1]+up[t*4+2]+up[t*4+3];
    float u = sqrtf(tot*(1.f/192.f));
    float vg = sc[0][t]>0.f?1.f:0.f;
    float vb = sc[1][t]>0.f?1.f:0.f;
    float vh = sc[2][t]>0.f?1.f:0.f;
    float cov = fminf(fmaxf((vg+vb+vh)*(1.f/3.f),0.f),1.f);
    s_cov[t] = cov; s_unc[t] = u;
    out_cov[(size_t)b*P_ + p0 + t] = cov;
    raw_unc[(size_t)b*P_ + p0 + t] = u;
    atomicMax(&scale[b], __float_as_int(u));
  }
  __syncthreads();
  // pack NHWC bf16: 64 px x 28 groups of 8 ch
  for (int f=t; f<1792; f+=256){
    int cg = f % 28, bl = f / 28;
    int c0 = cg*8;
    unsigned short h[8];
    #pragma unroll
    for (int j=0;j<8;j++){
      int c = c0+j;
      float vv;
      if (c < 192)      vv = sv[bl*193+c];
      else if (c==192)  vv = s_cov[bl];
      else if (c==193)  vv = s_unc[bl];
      else              vv = 0.f;
      h[j] = f2bf(vv);
    }
    *(uint4*)&ctxb[((size_t)b*P_ + p0 + bl)*ICP1 + c0] = *(uint4*)h;
  }
}

// ---------------- K3: normalize uncertainty ----------------
__global__ __launch_bounds__(256) void k_norm_unc(unsigned short* __restrict__ ctxb,
    const int* __restrict__ scale, const float* __restrict__ raw_unc,
    const float* __restrict__ out_cov, float* __restrict__ out_unc)
{
  int tid = blockIdx.x*256 + threadIdx.x;
  int b = tid >> 16;
  float s = fmaxf(__int_as_float(scale[b]), 1e-6f);
  float u = raw_unc[tid];
  float cov = out_cov[tid];
  float un = fminf(fmaxf(u/s,0.f),1.f)*cov;
  out_unc[tid] = un;
  ctxb[(size_t)tid*ICP1 + 193] = f2bf(un);
}

// ---------------- conv 3x3 via MFMA bf16 implicit GEMM ----------------
// in: NHWC bf16 [b][256][256][ICP]; Wp: [9][192][ICP] bf16; out: NHWC fp32 [b][256][256][192]
// block 256 thr = 4 waves. tile: 64 oc x 128 px (one row). K-chunks of 32 ic.
template<int ICP, int CHUNKS>
__global__ __launch_bounds__(256,2) void k_conv3(const unsigned short* __restrict__ X,
    const unsigned short* __restrict__ Wp, const float* __restrict__ bias, float* __restrict__ Y)
{
  __shared__ short s_in[3*132*32];   // 25,344 B, XOR-swizzled
  __shared__ short s_w[9*64*32];     // 36,864 B, XOR-swizzled
  int t = threadIdx.x;
  int x0 = blockIdx.x*128, y0 = blockIdx.y;
  int bz = blockIdx.z; int b = bz/3; int oc0 = (bz%3)*64;
  int wv = t>>6, lane = t&63, l15 = lane&15, quad = lane>>4;
  f32x4 acc[4][2];
  #pragma unroll
  for (int mt=0;mt<4;mt++){
    float4 bv = *(const float4*)&bias[oc0 + mt*16 + quad*4];
    f32x4 iv; iv.x=bv.x; iv.y=bv.y; iv.z=bv.z; iv.w=bv.w;
    acc[mt][0]=iv; acc[mt][1]=iv;
  }
  const unsigned short* Xb = X + (size_t)b*P_*ICP;
  for (int ch=0; ch<CHUNKS; ++ch){
    int ic0 = ch*32;
    __syncthreads();
    for (int f=t; f<1560; f+=256){
      int icq = f&3; int g = f>>2; int xi = g%130; int row = g/130;
      int gx = x0 + xi - 1, gy = y0 + row - 1;
      uint4 vval = make_uint4(0,0,0,0);
      if ((unsigned)gx < 256u && (unsigned)gy < 256u)
        vval = *(const uint4*)&Xb[(size_t)(gy*256+gx)*ICP + ic0 + icq*8];
      int r = row*132 + xi;
      *(uint4*)&s_in[r*32 + ((icq ^ ((r>>1)&3))&3)*8] = vval;
    }
    for (int f=t; f<2304; f+=256){
      int icq = f&3; int oc = (f>>2)&63; int k = f>>8;
      uint4 vval = *(const uint4*)&Wp[(size_t)(k*192 + oc0 + oc)*ICP + ic0 + icq*8];
      int r = k*64 + oc;
      *(uint4*)&s_w[r*32 + ((icq ^ ((r>>1)&3))&3)*8] = vval;
    }
    __syncthreads();
    #pragma unroll
    for (int k=0;k<9;k++){
      const int ky = k/3, kx = k%3;
      bf16x8 Af[4], Bf[2];
      #pragma unroll
      for (int mt=0;mt<4;mt++){
        int r = k*64 + mt*16 + l15;
        Af[mt] = *(const bf16x8*)&s_w[r*32 + (((quad ^ (r>>1))&3))*8];
      }
      #pragma unroll
      for (int nt=0;nt<2;nt++){
        int x = wv*32 + nt*16 + l15 + kx;
        int r = ky*132 + x;
        Bf[nt] = *(const bf16x8*)&s_in[r*32 + (((quad ^ (r>>1))&3))*8];
      }
      #pragma unroll
      for (int mt=0;mt<4;mt++)
        #pragma unroll
        for (int nt=0;nt<2;nt++)
          acc[mt][nt] = __builtin_amdgcn_mfma_f32_16x16x32_bf16(Af[mt], Bf[nt], acc[mt][nt], 0, 0, 0);
    }
  }
  float* Yb = Y + (size_t)b*P_*192;
  #pragma unroll
  for (int mt=0;mt<4;mt++){
    int oc = oc0 + mt*16 + quad*4;
    #pragma unroll
    for (int nt=0;nt<2;nt++){
      int px = x0 + wv*32 + nt*16 + l15;
      *(f32x4*)&Yb[(size_t)(y0*256+px)*192 + oc] = acc[mt][nt];
    }
  }
}

// ---------------- group-norm stats over NHWC ----------------
__global__ __launch_bounds__(256) void k_gn_stats(const float* __restrict__ x, double* __restrict__ stats)
{
  int b = blockIdx.y; int y0 = blockIdx.x*2;
  const float* base = x + ((size_t)b*P_ + y0*256)*192;
  int t = threadIdx.x;
  double s1[3]={0,0,0}, s2[3]={0,0,0};
  for (int j=0;j<96;j++){
    int f4 = t + j*256;
    float4 v = *(const float4*)&base[(size_t)f4*4];
    int r = j - (j/3)*3;
    s1[r] += (double)v.x + (double)v.y + (double)v.z + (double)v.w;
    s2[r] += (double)v.x*v.x + (double)v.y*v.y + (double)v.z*v.z + (double)v.w*v.w;
  }
  __shared__ double red[16];
  if (t<16) red[t]=0.0;
  __syncthreads();
  #pragma unroll
  for (int r=0;r<3;r++){
    int c = (4*t + 64*r) % 192;
    int g = c/24;
    atomicAdd(&red[g*2],   s1[r]);
    atomicAdd(&red[g*2+1], s2[r]);
  }
  __syncthreads();
  if (t<8){
    atomicAdd(&stats[(b*8+t)*2],   red[t*2]);
    atomicAdd(&stats[(b*8+t)*2+1], red[t*2+1]);
  }
}

// ---------------- GN apply + SiLU -> bf16 NHWC (for conv2) ----------------
__global__ __launch_bounds__(256) void k_gn1_apply(const float* __restrict__ x, const double* __restrict__ stats,
    const float* __restrict__ gs, const float* __restrict__ gb, unsigned short* __restrict__ y)
{
  size_t i8 = ((size_t)blockIdx.x*256 + threadIdx.x)*8;
  int b = (int)(i8 / ((size_t)192*P_));
  int c = (int)(i8 % 192);
  int bg = b*8 + c/24;
  const double N = 24.0*65536.0;
  double mu = stats[bg*2]/N;
  double var = stats[bg*2+1]/N - mu*mu;
  float rstd = 1.0f/sqrtf((float)var + 1e-5f);
  float mean = (float)mu;
  float4 sA = *(const float4*)&gs[c];
  float4 sB = *(const float4*)&gs[c+4];
  float4 bA = *(const float4*)&gb[c];
  float4 bB = *(const float4*)&gb[c+4];
  float4 v0 = *(const float4*)&x[i8];
  float4 v1 = *(const float4*)&x[i8+4];
  float xin[8] = {v0.x,v0.y,v0.z,v0.w,v1.x,v1.y,v1.z,v1.w};
  float scl[8] = {sA.x,sA.y,sA.z,sA.w,sB.x,sB.y,sB.z,sB.w};
  float bia[8] = {bA.x,bA.y,bA.z,bA.w,bB.x,bB.y,bB.z,bB.w};
  unsigned short h[8];
  #pragma unroll
  for (int i=0;i<8;i++){
    float xn = (xin[i]-mean)*rstd*scl[i] + bia[i];
    h[i] = f2bf(xn*sigmoidf_(xn));
  }
  *(uint4*)&y[i8] = *(uint4*)h;
}

// ---------------- GN apply + SiLU in place fp32 (h2) ----------------
__global__ __launch_bounds__(256) void k_gn2_apply(float* __restrict__ x, const double* __restrict__ stats,
    const float* __restrict__ gs, const float* __restrict__ gb)
{
  size_t i8 = ((size_t)blockIdx.x*256 + threadIdx.x)*8;
  int b = (int)(i8 / ((size_t)192*P_));
  int c = (int)(i8 % 192);
  int bg = b*8 + c/24;
  const double N = 24.0*65536.0;
  double mu = stats[bg*2]/N;
  double var = stats[bg*2+1]/N - mu*mu;
  float rstd = 1.0f/sqrtf((float)var + 1e-5f);
  float mean = (float)mu;
  float4 sA = *(const float4*)&gs[c];
  float4 sB = *(const float4*)&gs[c+4];
  float4 bA = *(const float4*)&gb[c];
  float4 bB = *(const float4*)&gb[c+4];
  float4 v0 = *(const float4*)&x[i8];
  float4 v1 = *(const float4*)&x[i8+4];
  float xin[8] = {v0.x,v0.y,v0.z,v0.w,v1.x,v1.y,v1.z,v1.w};
  float scl[8] = {sA.x,sA.y,sA.z,sA.w,sB.x,sB.y,sB.z,sB.w};
  float bia[8] = {bA.x,bA.y,bA.z,bA.w,bB.x,bB.y,bB.z,bB.w};
  #pragma unroll
  for (int i=0;i<8;i++){
    float xn = (xin[i]-mean)*rstd*scl[i] + bia[i];
    xin[i] = xn*sigmoidf_(xn);
  }
  *(float4*)&x[i8]   = make_float4(xin[0],xin[1],xin[2],xin[3]);
  *(float4*)&x[i8+4] = make_float4(xin[4],xin[5],xin[6],xin[7]);
}

// ---------------- global average pool (NHWC) ----------------
__global__ __launch_bounds__(256) void k_pool(const float* __restrict__ x, float* __restrict__ pooled)
{
  int b = blockIdx.y; int y0 = blockIdx.x*4;
  const float* base = x + ((size_t)b*P_ + y0*256)*192;
  int t = threadIdx.x;
  float4 p[3];
  #pragma unroll
  for (int r=0;r<3;r++) p[r] = make_float4(0.f,0.f,0.f,0.f);
  for (int j=0;j<192;j++){
    int f4 = t + j*256;
    float4 v = *(const float4*)&base[(size_t)f4*4];
    int r = j - (j/3)*3;
    p[r].x += v.x; p[r].y += v.y; p[r].z += v.z; p[r].w += v.w;
  }
  __shared__ float pl[192];
  if (t<192) pl[t]=0.f;
  __syncthreads();
  #pragma unroll
  for (int r=0;r<3;r++){
    int c = (4*t + 64*r) % 192;
    atomicAdd(&pl[c],   p[r].x);
    atomicAdd(&pl[c+1], p[r].y);
    atomicAdd(&pl[c+2], p[r].z);
    atomicAdd(&pl[c+3], p[r].w);
  }
  __syncthreads();
  if (t<192) atomicAdd(&pooled[b*192+t], pl[t]*(1.f/65536.f));
}

// ---------------- channel gate MLP ----------------
__global__ void k_gate(const float* __restrict__ pooled, const float* __restrict__ gw1,
    const float* __restrict__ gb1, const float* __restrict__ gw2, const float* __restrict__ gb2,
    float* __restrict__ gatef)
{
  __shared__ float hb[2*48];
  int t = threadIdx.x;
  if (t<96){
    int b=t/48, j=t%48;
    float a = gb1[j];
    for (int c=0;c<192;c++) a = fmaf(pooled[b*192+c], gw1[j*192+c], a);
    hb[t] = a*sigmoidf_(a);
  }
  __syncthreads();
  for (int i=t;i<384;i+=256){
    int b=i/192, c=i%192;
    float a = gb2[c];
    for (int j=0;j<48;j++) a = fmaf(hb[b*48+j], gw2[c*48+j], a);
    gatef[i] = 0.5f + sigmoidf_(a);
  }
}

// ---------------- confidence head (bf16 ctx NHWC) ----------------
__global__ __launch_bounds__(256) void k_conf(const unsigned short* __restrict__ ctxb,
    const float* __restrict__ cw, const float* __restrict__ cbias, float* __restrict__ out_conf)
{
  __shared__ float scw[3*224];
  int t = threadIdx.x;
  for (int f=t; f<672; f+=256){
    int c = f % 224, o = f / 224;
    scw[f] = (c<194) ? cw[o*194 + c] : 0.f;
  }
  __syncthreads();
  int tid = blockIdx.x*256 + t;
  int b = tid >> 16, p = tid & 65535;
  const unsigned short* cp = ctxb + ((size_t)b*P_ + p)*ICP1;
  float a0 = cbias[0], a1 = cbias[1], a2 = cbias[2];
  for (int q=0;q<28;q++){
    uint4 v = *(const uint4*)&cp[q*8];
    unsigned wd[4] = {v.x,v.y,v.z,v.w};
    #pragma unroll
    for (int j=0;j<8;j++){
      unsigned bits = wd[j>>1];
      float xf = (j&1) ? __uint_as_float(bits & 0xffff0000u) : __uint_as_float(bits<<16);
      int c = q*8+j;
      a0 = fmaf(xf, scw[c],       a0);
      a1 = fmaf(xf, scw[224+c],   a1);
      a2 = fmaf(xf, scw[448+c],   a2);
    }
  }
  out_conf[((size_t)(b*3+0))*P_ + p] = sigmoidf_(a0);
  out_conf[((size_t)(b*3+1))*P_ + p] = sigmoidf_(a1);
  out_conf[((size_t)(b*3+2))*P_ + p] = sigmoidf_(a2);
}

// ---------------- 1x1 residual GEMM + final mix ----------------
// block: 256 px x 32 oc. thread: pxt=t&31 -> px {pxt+32i}, tg=t>>5 -> oc {oc0+tg*4+j}
__global__ __launch_bounds__(256) void k_combine(const unsigned short* __restrict__ ctxb,
    const float* __restrict__ h2, const float* __restrict__ rpw, const float* __restrict__ rpb,
    const float* __restrict__ gatef, const float* __restrict__ conf_out,
    const float* __restrict__ rs, const float* __restrict__ mix, float* __restrict__ dout)
{
  __shared__ short s_x[256*32];      // bf16, XOR-swizzled rows
  __shared__ float s_w[32*36];
  __shared__ float s_h[256*33];
  int t = threadIdx.x;
  int p0 = blockIdx.x*256;
  int oc0 = blockIdx.y*32;
  int b = blockIdx.z;
  int pxt = t&31, tg = t>>5;
  int sw = (pxt>>1)&3;
  // stage h2 tile (32 oc x 256 px)
  for (int f=t; f<8192; f+=256){
    int oc = f&31, px = f>>5;
    s_h[px*33 + oc] = h2[((size_t)b*P_ + p0 + px)*192 + oc0 + oc];
  }
  float acc[8][4];
  #pragma unroll
  for (int j=0;j<4;j++){
    float bv = rpb[oc0+tg*4+j];
    #pragma unroll
    for (int i=0;i<8;i++) acc[i][j]=bv;
  }
  float fv[8][4];
  for (int cb=0; cb<7; cb++){
    int c0 = cb*32;
    __syncthreads();
    for (int f=t; f<1024; f+=256){
      int icq = f&3, px = f>>2;
      uint4 v = *(const uint4*)&ctxb[((size_t)b*P_ + p0 + px)*ICP1 + c0 + icq*8];
      *(uint4*)&s_x[px*32 + ((icq ^ ((px>>1)&3))&3)*8] = v;
    }
    for (int f=t; f<1024; f+=256){
      int cl = f&31, ocl = f>>5;
      int c = c0+cl;
      s_w[cl*36 + ocl] = (c<194) ? rpw[(size_t)(oc0+ocl)*194 + c] : 0.f;
    }
    __syncthreads();
    if (cb == blockIdx.y){
      #pragma unroll
      for (int i=0;i<8;i++){
        int px = pxt + 32*i;
        int blk = tg>>1;
        const ushort4 hv = *(const ushort4*)&s_x[px*32 + (((blk ^ (px>>1))&3))*8 + (tg&1)*4];
        fv[i][0] = bf2f(hv.x); fv[i][1] = bf2f(hv.y); fv[i][2] = bf2f(hv.z); fv[i][3] = bf2f(hv.w);
      }
    }
    #pragma unroll 1
    for (int j2=0;j2<4;j2++){
      uint4 xq[8];
      #pragma unroll
      for (int i=0;i<8;i++){
        int px = pxt + 32*i;
        xq[i] = *(const uint4*)&s_x[px*32 + ((j2 ^ sw)&3)*8];
      }
      #pragma unroll
      for (int j=0;j<8;j++){
        int cl = j2*8 + j;
        float4 wv = *(const float4*)&s_w[cl*36 + tg*4];
        #pragma unroll
        for (int i=0;i<8;i++){
          unsigned bits = (&xq[i].x)[j>>1];
          float xf = (j&1) ? __uint_as_float(bits & 0xffff0000u) : __uint_as_float(bits<<16);
          acc[i][0] = fmaf(xf, wv.x, acc[i][0]);
          acc[i][1] = fmaf(xf, wv.y, acc[i][1]);
          acc[i][2] = fmaf(xf, wv.z, acc[i][2]);
          acc[i][3] = fmaf(xf, wv.w, acc[i][3]);
        }
      }
    }
  }
  float trs = tanhf(rs[0]);
  float ms  = tanhf(mix[0]);
  int br = oc0 >> 6;
  float cf[8];
  #pragma unroll
  for (int i=0;i<8;i++)
    cf[i] = conf_out[((size_t)(b*3+br))*P_ + p0 + pxt + 32*i];
  #pragma unroll
  for (int j=0;j<4;j++){
    int oc = oc0+tg*4+j;
    int cc = oc & 63;
    float gv = gatef[b*192+oc];
    #pragma unroll
    for (int i=0;i<8;i++){
      int px = pxt + 32*i;
      float hv = s_h[px*33 + tg*4 + j];
      float ov = fv[i][j] + ms * (hv*gv + trs*acc[i][j]) * cf[i];
      dout[(size_t)br*OUT_B + ((size_t)(b*64+cc))*P_ + p0 + px] = ov;
    }
  }
}

extern "C" void kernel_launch(void* const* d_in, const int* in_sizes, int n_in,
                              void* d_out, int out_size, void* d_ws, size_t ws_size,
                              hipStream_t stream)
{
  const float* vf    = (const float*)d_in[0];
  const float* uvs   = (const float*)d_in[1];
  const float* masks = (const float*)d_in[2];
  const float* wg    = (const float*)d_in[3];
  const float* wb    = (const float*)d_in[4];
  const float* wh    = (const float*)d_in[5];
  const float* c1w = (const float*)d_in[7];
  const float* c1b = (const float*)d_in[8];
  const float* g1s = (const float*)d_in[9];
  const float* g1b = (const float*)d_in[10];
  const float* c2w = (const float*)d_in[11];
  const float* c2b = (const float*)d_in[12];
  const float* g2s = (const float*)d_in[13];
  const float* g2b = (const float*)d_in[14];
  const float* gw1 = (const float*)d_in[15];
  const float* gb1 = (const float*)d_in[16];
  const float* gw2 = (const float*)d_in[17];
  const float* gb2 = (const float*)d_in[18];
  const float* rpw = (const float*)d_in[19];
  const float* rpb = (const float*)d_in[20];
  const float* rs  = (const float*)d_in[21];
  const float* cw  = (const float*)d_in[22];
  const float* cb  = (const float*)d_in[23];
  const float* mix = (const float*)d_in[24];

  char* ws = (char*)d_ws;
  float*          accb  = (float*)(ws + OFF_ACC);
  float*          cntb  = (float*)(ws + OFF_CNT);
  unsigned short* ctxb  = (unsigned short*)(ws + OFF_CTXB);
  unsigned short* h1act = (unsigned short*)(ws + OFF_H1A);
  unsigned short* w1p   = (unsigned short*)(ws + OFF_W1);
  unsigned short* w2p   = (unsigned short*)(ws + OFF_W2);
  float*  h1raw  = (float*)(ws + OFF_ACC);   // overlays atlas acc (dead after finalize)
  float*  h2     = (float*)(ws + OFF_ACC);   // overlays h1raw (dead after gn1_apply)
  double* stats1 = (double*)(ws + OFF_SM + SM_STATS1);
  double* stats2 = (double*)(ws + OFF_SM + SM_STATS2);
  int*    scale  = (int*)(ws + OFF_SM + SM_SCALE);
  float*  pooled = (float*)(ws + OFF_SM + SM_POOLED);
  float*  gatef  = (float*)(ws + OFF_SM + SM_GATE);
  float*  rawu   = (float*)(ws + OFF_SM + SM_RAWU);

  float* out = (float*)d_out;
  float* out_cov  = out + OUT_COV;
  float* out_unc  = out + OUT_UNC;
  float* out_conf = out + OUT_CONF;

  hipMemsetAsync(ws + OFF_ACC, 0, SZ_ACC + SZ_CNT, stream);
  hipMemsetAsync(ws + OFF_SM, 0, 8192, stream);

  k_prep<<<2808, 256, 0, stream>>>(c1w, c2w, w1p, w2p);
  k_fuse<<<4096, 256, 0, stream>>>(vf, uvs, masks, wg, wb, wh, accb, cntb);
  k_finalize<<<2048, 256, 0, stream>>>(accb, cntb, ctxb, out_cov, rawu, scale);
  k_norm_unc<<<512, 256, 0, stream>>>(ctxb, scale, rawu, out_cov, out_unc);
  k_conv3<ICP1,7><<<dim3(2,256,6), 256, 0, stream>>>(ctxb, w1p, c1b, h1raw);
  k_gn_stats<<<dim3(128,2), 256, 0, stream>>>(h1raw, stats1);
  k_gn1_apply<<<12288, 256, 0, stream>>>(h1raw, stats1, g1s, g1b, h1act);
  k_conv3<ICP2,6><<<dim3(2,256,6), 256, 0, stream>>>(h1act, w2p, c2b, h2);
  k_gn_stats<<<dim3(128,2), 256, 0, stream>>>(h2, stats2);
  k_gn2_apply<<<12288, 256, 0, stream>>>(h2, stats2, g2s, g2b);
  k_pool<<<dim3(64,2), 256, 0, stream>>>(h2, pooled);
  k_gate<<<1, 256, 0, stream>>>(pooled, gw1, gb1, gw2, gb2, gatef);
  k_conf<<<512, 256, 0, stream>>>(ctxb, cw, cb, out_conf);
  k_combine<<<dim3(256,6,2), 256, 0, stream>>>(ctxb, h2, rpw, rpb, gatef, out_conf, rs, mix, out);
}

// Round 3
// 863.383 us; speedup vs baseline: 4.1651x; 1.4582x over previous
//
#include <hip/hip_runtime.h>
#include <math.h>

#define B_ 2
#define V_ 8
#define C_ 64
#define HW_ 16384
#define A_ 256
#define P_ 65536
#define CO_ 192
#define CPG_ 24
#define NG_ 8
#define ICP1 224
#define ICP2 192

// workspace layout (bytes)
#define OFF_ACC   0ull
#define SZ_ACC    (2ull*65536*192*4)          // 100,663,296 ; reused for h1raw then h2
#define OFF_CNT   (OFF_ACC + SZ_ACC)
#define SZ_CNT    (2ull*3*65536*4)
#define OFF_CTXB  (OFF_CNT + SZ_CNT)          // ctx NHWC bf16, 224-ch padded
#define SZ_CTXB   (2ull*65536*224*2)
#define OFF_H1A   (OFF_CTXB + SZ_CTXB)        // h1 activated, NHWC bf16, 192 ch
#define SZ_H1A    (2ull*65536*192*2)
#define OFF_W1    (OFF_H1A + SZ_H1A)
#define SZ_W1     (9ull*192*224*2)
#define OFF_W2    (OFF_W1 + SZ_W1)
#define SZ_W2     (9ull*192*192*2)
#define OFF_SM    (OFF_W2 + SZ_W2 + 256)

// small-region offsets (within OFF_SM)
#define SM_STATS1 0
#define SM_STATS2 256
#define SM_SCALE  512
#define SM_POOLED 1024
#define SM_GATE   2560
#define SM_RAWU   8192

// d_out offsets (floats)
#define OUT_B    8388608
#define OUT_COV  25165824
#define OUT_UNC  25296896
#define OUT_CONF 25427968

typedef __attribute__((ext_vector_type(4))) float f32x4;
typedef __attribute__((ext_vector_type(8))) short bf16x8;

__device__ __forceinline__ float sigmoidf_(float x){ return 1.f/(1.f+expf(-x)); }
__device__ __forceinline__ float bf2f(unsigned short h){ return __uint_as_float(((unsigned)h)<<16); }
__device__ __forceinline__ unsigned short f2bf(float f){
  unsigned u = __float_as_uint(f);
  return (unsigned short)((u + 0x7fffu + ((u>>16)&1u)) >> 16);
}

// ---------------- K0: weight prep (transpose+pad+bf16) ----------------
__global__ __launch_bounds__(256) void k_prep(const float* __restrict__ c1w,
    const float* __restrict__ c2w, unsigned short* __restrict__ w1p, unsigned short* __restrict__ w2p)
{
  int idx = blockIdx.x*256 + threadIdx.x;
  const int N1 = 9*192*224;
  if (idx < N1){
    int ic = idx % 224; int oc = (idx/224) % 192; int k = idx/(224*192);
    float v = (ic < 194) ? c1w[(size_t)(oc*194+ic)*9 + k] : 0.f;
    w1p[idx] = f2bf(v);
  } else {
    int i2 = idx - N1;
    if (i2 < 9*192*192){
      int ic = i2 % 192; int oc = (i2/192) % 192; int k = i2/(192*192);
      w2p[i2] = f2bf(c2w[(size_t)(oc*192+ic)*9 + k]);
    }
  }
}

// ---------------- K1: fused tri-branch scatter ----------------
__global__ __launch_bounds__(256) void k_fuse(const float* __restrict__ vf,
    const float* __restrict__ uvs, const float* __restrict__ masks,
    const float* __restrict__ wgp, const float* __restrict__ wbp, const float* __restrict__ whp,
    float* __restrict__ acc, float* __restrict__ cnt)
{
  __shared__ __align__(16) float sf[64*65];
  __shared__ int sidx[64];
  __shared__ int svalid[64];
  __shared__ float sw[3];
  int t = threadIdx.x;
  int pix0 = blockIdx.x*64;
  int b   = pix0 / (V_*HW_);
  int rem = pix0 % (V_*HW_);
  int v   = rem / HW_;
  int p2  = rem % HW_;
  size_t vbase = ((size_t)(b*V_+v))*C_*HW_;
  for (int i=0;i<16;i++){
    int f = t + i*256;
    int c = f>>6, px = f&63;
    sf[c*65+px] = vf[vbase + (size_t)c*HW_ + p2 + px];
  }
  if (t<64){
    const float* u2 = uvs + (((size_t)(b*V_+v))*HW_ + p2 + t)*2;
    float ux = u2[0], uy = u2[1];
    int fin = isfinite(ux) && isfinite(uy);
    float su = fin?ux:0.f, svv = fin?uy:0.f;
    float cu = fminf(fmaxf(su,0.f),1.f);
    float cv = fminf(fmaxf(svv,0.f),1.f);
    int xi = (int)rintf(cu*255.f);
    int yi = (int)rintf((1.f-cv)*255.f);
    sidx[t] = yi*256+xi;
    float m = masks[((size_t)(b*V_+v))*HW_ + p2 + t];
    svalid[t] = (m>0.5f) && fin;
  }
  if (t<3){
    const float* wp = (t==0)?wgp:((t==1)?wbp:whp);
    sw[t] = fmaxf(wp[b*V_+v], 0.f);
  }
  __syncthreads();
  int wave = t>>6, lane = t&63;
  float w0 = sw[0], w1 = sw[1], w2 = sw[2];
  for (int i=0;i<16;i++){
    int px = wave*16+i;
    if (!svalid[px]) continue;
    int bin = sidx[px];
    float val = sf[lane*65+px];
    size_t base = ((size_t)b*P_ + bin)*192;
    if (w0>0.f) atomicAdd(&acc[base + lane],        val*w0);
    if (w1>0.f) atomicAdd(&acc[base + 64 + lane],   val*w1);
    if (w2>0.f) atomicAdd(&acc[base + 128 + lane],  val*w2);
    if (lane<3){
      float wv = sw[lane];
      if (wv>0.f) atomicAdd(&cnt[((size_t)(b*3+lane))*P_ + bin], wv);
    }
  }
}

// ---------------- K2: finalize atlases -> ctx bf16 NHWC, coverage, raw unc ----------------
__global__ __launch_bounds__(256) void k_finalize(const float* __restrict__ acc,
      const float* __restrict__ cnt, unsigned short* __restrict__ ctxb,
      float* __restrict__ out_cov, float* __restrict__ raw_unc, int* __restrict__ scale)
{
  __shared__ __align__(16) float sv[64*193];
  __shared__ float sc[3][64];
  __shared__ float up[256];
  __shared__ float s_cov[64];
  __shared__ float s_unc[64];
  int t = threadIdx.x;
  int bin0 = blockIdx.x*64;
  int b = bin0 >> 16;
  int p0 = bin0 & 65535;
  size_t abase = ((size_t)b*P_ + p0)*192;
  for (int i=0;i<48;i++){
    int f = t + i*256;
    int bl = f/192, c = f - bl*192;
    sv[bl*193+c] = acc[abase + f];
  }
  if (t<192){
    int br = t>>6, bl = t&63;
    sc[br][bl] = cnt[((size_t)(b*3+br))*P_ + p0 + bl];
  }
  __syncthreads();
  {
    int bl = t>>2, q = t&3;
    float dg = 1.f/fmaxf(sc[0][bl],1.f);
    float db = 1.f/fmaxf(sc[1][bl],1.f);
    float dh = 1.f/fmaxf(sc[2][bl],1.f);
    float s = 0.f;
    for (int j=0;j<16;j++){
      int c = q*16+j;
      float fg = sv[bl*193+c]*dg;
      float fb = sv[bl*193+64+c]*db;
      float fh = sv[bl*193+128+c]*dh;
      sv[bl*193+c]=fg; sv[bl*193+64+c]=fb; sv[bl*193+128+c]=fh;
      float m = (fg+fb+fh)*(1.f/3.f);
      float d0=fg-m, d1=fb-m, d2=fh-m;
      s += d0*d0+d1*d1+d2*d2;
    }
    up[t] = s;
  }
  __syncthreads();
  if (t<64){
    float tot = up[t*4]+up[t*4+1]+up[t*4+2]+up[t*4+3];
    float u = sqrtf(tot*(1.f/192.f));
    float vg = sc[0][t]>0.f?1.f:0.f;
    float vb = sc[1][t]>0.f?1.f:0.f;
    float vh = sc[2][t]>0.f?1.f:0.f;
    float cov = fminf(fmaxf((vg+vb+vh)*(1.f/3.f),0.f),1.f);
    s_cov[t] = cov; s_unc[t] = u;
    out_cov[(size_t)b*P_ + p0 + t] = cov;
    raw_unc[(size_t)b*P_ + p0 + t] = u;
    atomicMax(&scale[b], __float_as_int(u));
  }
  __syncthreads();
  // pack NHWC bf16: 64 px x 28 groups of 8 ch
  for (int f=t; f<1792; f+=256){
    int cg = f % 28, bl = f / 28;
    int c0 = cg*8;
    unsigned short h[8];
    #pragma unroll
    for (int j=0;j<8;j++){
      int c = c0+j;
      float vv;
      if (c < 192)      vv = sv[bl*193+c];
      else if (c==192)  vv = s_cov[bl];
      else if (c==193)  vv = s_unc[bl];
      else              vv = 0.f;
      h[j] = f2bf(vv);
    }
    *(uint4*)&ctxb[((size_t)b*P_ + p0 + bl)*ICP1 + c0] = *(uint4*)h;
  }
}

// ---------------- K3: normalize uncertainty ----------------
__global__ __launch_bounds__(256) void k_norm_unc(unsigned short* __restrict__ ctxb,
    const int* __restrict__ scale, const float* __restrict__ raw_unc,
    const float* __restrict__ out_cov, float* __restrict__ out_unc)
{
  int tid = blockIdx.x*256 + threadIdx.x;
  int b = tid >> 16;
  float s = fmaxf(__int_as_float(scale[b]), 1e-6f);
  float u = raw_unc[tid];
  float cov = out_cov[tid];
  float un = fminf(fmaxf(u/s,0.f),1.f)*cov;
  out_unc[tid] = un;
  ctxb[(size_t)tid*ICP1 + 193] = f2bf(un);
}

// ---------------- conv 3x3 via MFMA bf16 implicit GEMM, ky-split staging ----------------
// in: NHWC bf16 [b][256][256][ICP]; Wp: [9][192][ICP] bf16; out: NHWC fp32 [b][256][256][192]
// block 256 thr = 4 waves; tile: 64 oc x 256 px (one full row). Wave tile 64x64 (4x4 MFMA).
// Per stage (chunk,ky): stage 1 input row (258x32ic) + 3-kx weight slice. LDS 28.8 KB.
template<int ICP, int CHUNKS>
__global__ __launch_bounds__(256,4) void k_conv3(const unsigned short* __restrict__ X,
    const unsigned short* __restrict__ Wp, const float* __restrict__ bias, float* __restrict__ Y)
{
  __shared__ short s_in[258*32];   // 16,512 B, XOR-swizzled rows (px)
  __shared__ short s_w[192*32];    // 12,288 B, rows = kx*64+oc
  int t = threadIdx.x;
  int y0 = blockIdx.x;
  int oc0 = blockIdx.y*64;
  int b = blockIdx.z;
  int wv = t>>6, lane = t&63, l15 = lane&15, quad = lane>>4;
  f32x4 acc[4][4];
  #pragma unroll
  for (int mt=0;mt<4;mt++){
    float4 bv = *(const float4*)&bias[oc0 + mt*16 + quad*4];
    f32x4 iv; iv.x=bv.x; iv.y=bv.y; iv.z=bv.z; iv.w=bv.w;
    #pragma unroll
    for (int nt=0;nt<4;nt++) acc[mt][nt]=iv;
  }
  const unsigned short* Xb = X + (size_t)b*P_*ICP;
  for (int ch=0; ch<CHUNKS; ++ch){
    int ic0 = ch*32;
    for (int ky=0; ky<3; ky++){
      int gy = y0 + ky - 1;
      if ((unsigned)gy >= 256u) continue;        // block-uniform skip (zero contribution)
      __syncthreads();
      // stage input row gy: 258 px x 32 ic (1032 uint4)
      for (int f=t; f<1032; f+=256){
        int icq = f&3, xi = f>>2;
        int gx = xi - 1;
        uint4 vval = make_uint4(0,0,0,0);
        if ((unsigned)gx < 256u)
          vval = *(const uint4*)&Xb[(size_t)(gy*256+gx)*ICP + ic0 + icq*8];
        *(uint4*)&s_in[xi*32 + ((icq ^ ((xi>>1)&3)))*8] = vval;
      }
      // stage weights for this ky: 3 kx x 64 oc x 32 ic (768 uint4)
      for (int f=t; f<768; f+=256){
        int icq = f&3, oc = (f>>2)&63, kx = f>>8;
        uint4 vval = *(const uint4*)&Wp[(size_t)((ky*3+kx)*192 + oc0 + oc)*ICP + ic0 + icq*8];
        int r = kx*64 + oc;
        *(uint4*)&s_w[r*32 + ((icq ^ ((r>>1)&3)))*8] = vval;
      }
      __syncthreads();
      #pragma unroll
      for (int kx=0;kx<3;kx++){
        bf16x8 Af[4], Bf[4];
        #pragma unroll
        for (int mt=0;mt<4;mt++){
          int r = kx*64 + mt*16 + l15;
          Af[mt] = *(const bf16x8*)&s_w[r*32 + (((quad ^ ((r>>1)&3)))&3)*8];
        }
        #pragma unroll
        for (int nt=0;nt<4;nt++){
          int r = wv*64 + nt*16 + l15 + kx;
          Bf[nt] = *(const bf16x8*)&s_in[r*32 + (((quad ^ ((r>>1)&3)))&3)*8];
        }
        #pragma unroll
        for (int mt=0;mt<4;mt++)
          #pragma unroll
          for (int nt=0;nt<4;nt++)
            acc[mt][nt] = __builtin_amdgcn_mfma_f32_16x16x32_bf16(Af[mt], Bf[nt], acc[mt][nt], 0, 0, 0);
      }
    }
  }
  float* Yb = Y + (size_t)b*P_*192;
  #pragma unroll
  for (int mt=0;mt<4;mt++){
    int oc = oc0 + mt*16 + quad*4;
    #pragma unroll
    for (int nt=0;nt<4;nt++){
      int px = wv*64 + nt*16 + l15;
      *(f32x4*)&Yb[(size_t)(y0*256+px)*192 + oc] = acc[mt][nt];
    }
  }
}

// ---------------- group-norm stats over NHWC ----------------
__global__ __launch_bounds__(256) void k_gn_stats(const float* __restrict__ x, double* __restrict__ stats)
{
  int b = blockIdx.y; int y0 = blockIdx.x*2;
  const float* base = x + ((size_t)b*P_ + y0*256)*192;
  int t = threadIdx.x;
  double s1[3]={0,0,0}, s2[3]={0,0,0};
  for (int j=0;j<96;j++){
    int f4 = t + j*256;
    float4 v = *(const float4*)&base[(size_t)f4*4];
    int r = j - (j/3)*3;
    s1[r] += (double)v.x + (double)v.y + (double)v.z + (double)v.w;
    s2[r] += (double)v.x*v.x + (double)v.y*v.y + (double)v.z*v.z + (double)v.w*v.w;
  }
  __shared__ double red[16];
  if (t<16) red[t]=0.0;
  __syncthreads();
  #pragma unroll
  for (int r=0;r<3;r++){
    int c = (4*t + 64*r) % 192;
    int g = c/24;
    atomicAdd(&red[g*2],   s1[r]);
    atomicAdd(&red[g*2+1], s2[r]);
  }
  __syncthreads();
  if (t<8){
    atomicAdd(&stats[(b*8+t)*2],   red[t*2]);
    atomicAdd(&stats[(b*8+t)*2+1], red[t*2+1]);
  }
}

// ---------------- GN apply + SiLU -> bf16 NHWC (for conv2) ----------------
__global__ __launch_bounds__(256) void k_gn1_apply(const float* __restrict__ x, const double* __restrict__ stats,
    const float* __restrict__ gs, const float* __restrict__ gb, unsigned short* __restrict__ y)
{
  size_t i8 = ((size_t)blockIdx.x*256 + threadIdx.x)*8;
  int b = (int)(i8 / ((size_t)192*P_));
  int c = (int)(i8 % 192);
  int bg = b*8 + c/24;
  const double N = 24.0*65536.0;
  double mu = stats[bg*2]/N;
  double var = stats[bg*2+1]/N - mu*mu;
  float rstd = 1.0f/sqrtf((float)var + 1e-5f);
  float mean = (float)mu;
  float4 sA = *(const float4*)&gs[c];
  float4 sB = *(const float4*)&gs[c+4];
  float4 bA = *(const float4*)&gb[c];
  float4 bB = *(const float4*)&gb[c+4];
  float4 v0 = *(const float4*)&x[i8];
  float4 v1 = *(const float4*)&x[i8+4];
  float xin[8] = {v0.x,v0.y,v0.z,v0.w,v1.x,v1.y,v1.z,v1.w};
  float scl[8] = {sA.x,sA.y,sA.z,sA.w,sB.x,sB.y,sB.z,sB.w};
  float bia[8] = {bA.x,bA.y,bA.z,bA.w,bB.x,bB.y,bB.z,bB.w};
  unsigned short h[8];
  #pragma unroll
  for (int i=0;i<8;i++){
    float xn = (xin[i]-mean)*rstd*scl[i] + bia[i];
    h[i] = f2bf(xn*sigmoidf_(xn));
  }
  *(uint4*)&y[i8] = *(uint4*)h;
}

// ---------------- GN apply + SiLU in place fp32 (h2) ----------------
__global__ __launch_bounds__(256) void k_gn2_apply(float* __restrict__ x, const double* __restrict__ stats,
    const float* __restrict__ gs, const float* __restrict__ gb)
{
  size_t i8 = ((size_t)blockIdx.x*256 + threadIdx.x)*8;
  int b = (int)(i8 / ((size_t)192*P_));
  int c = (int)(i8 % 192);
  int bg = b*8 + c/24;
  const double N = 24.0*65536.0;
  double mu = stats[bg*2]/N;
  double var = stats[bg*2+1]/N - mu*mu;
  float rstd = 1.0f/sqrtf((float)var + 1e-5f);
  float mean = (float)mu;
  float4 sA = *(const float4*)&gs[c];
  float4 sB = *(const float4*)&gs[c+4];
  float4 bA = *(const float4*)&gb[c];
  float4 bB = *(const float4*)&gb[c+4];
  float4 v0 = *(const float4*)&x[i8];
  float4 v1 = *(const float4*)&x[i8+4];
  float xin[8] = {v0.x,v0.y,v0.z,v0.w,v1.x,v1.y,v1.z,v1.w};
  float scl[8] = {sA.x,sA.y,sA.z,sA.w,sB.x,sB.y,sB.z,sB.w};
  float bia[8] = {bA.x,bA.y,bA.z,bA.w,bB.x,bB.y,bB.z,bB.w};
  #pragma unroll
  for (int i=0;i<8;i++){
    float xn = (xin[i]-mean)*rstd*scl[i] + bia[i];
    xin[i] = xn*sigmoidf_(xn);
  }
  *(float4*)&x[i8]   = make_float4(xin[0],xin[1],xin[2],xin[3]);
  *(float4*)&x[i8+4] = make_float4(xin[4],xin[5],xin[6],xin[7]);
}

// ---------------- global average pool (NHWC) ----------------
__global__ __launch_bounds__(256) void k_pool(const float* __restrict__ x, float* __restrict__ pooled)
{
  int b = blockIdx.y; int y0 = blockIdx.x*4;
  const float* base = x + ((size_t)b*P_ + y0*256)*192;
  int t = threadIdx.x;
  float4 p[3];
  #pragma unroll
  for (int r=0;r<3;r++) p[r] = make_float4(0.f,0.f,0.f,0.f);
  for (int j=0;j<192;j++){
    int f4 = t + j*256;
    float4 v = *(const float4*)&base[(size_t)f4*4];
    int r = j - (j/3)*3;
    p[r].x += v.x; p[r].y += v.y; p[r].z += v.z; p[r].w += v.w;
  }
  __shared__ float pl[192];
  if (t<192) pl[t]=0.f;
  __syncthreads();
  #pragma unroll
  for (int r=0;r<3;r++){
    int c = (4*t + 64*r) % 192;
    atomicAdd(&pl[c],   p[r].x);
    atomicAdd(&pl[c+1], p[r].y);
    atomicAdd(&pl[c+2], p[r].z);
    atomicAdd(&pl[c+3], p[r].w);
  }
  __syncthreads();
  if (t<192) atomicAdd(&pooled[b*192+t], pl[t]*(1.f/65536.f));
}

// ---------------- channel gate MLP ----------------
__global__ void k_gate(const float* __restrict__ pooled, const float* __restrict__ gw1,
    const float* __restrict__ gb1, const float* __restrict__ gw2, const float* __restrict__ gb2,
    float* __restrict__ gatef)
{
  __shared__ float hb[2*48];
  int t = threadIdx.x;
  if (t<96){
    int b=t/48, j=t%48;
    float a = gb1[j];
    for (int c=0;c<192;c++) a = fmaf(pooled[b*192+c], gw1[j*192+c], a);
    hb[t] = a*sigmoidf_(a);
  }
  __syncthreads();
  for (int i=t;i<384;i+=256){
    int b=i/192, c=i%192;
    float a = gb2[c];
    for (int j=0;j<48;j++) a = fmaf(hb[b*48+j], gw2[c*48+j], a);
    gatef[i] = 0.5f + sigmoidf_(a);
  }
}

// ---------------- confidence head (bf16 ctx NHWC) ----------------
__global__ __launch_bounds__(256) void k_conf(const unsigned short* __restrict__ ctxb,
    const float* __restrict__ cw, const float* __restrict__ cbias, float* __restrict__ out_conf)
{
  __shared__ float scw[3*224];
  int t = threadIdx.x;
  for (int f=t; f<672; f+=256){
    int c = f % 224, o = f / 224;
    scw[f] = (c<194) ? cw[o*194 + c] : 0.f;
  }
  __syncthreads();
  int tid = blockIdx.x*256 + t;
  int b = tid >> 16, p = tid & 65535;
  const unsigned short* cp = ctxb + ((size_t)b*P_ + p)*ICP1;
  float a0 = cbias[0], a1 = cbias[1], a2 = cbias[2];
  for (int q=0;q<28;q++){
    uint4 v = *(const uint4*)&cp[q*8];
    unsigned wd[4] = {v.x,v.y,v.z,v.w};
    #pragma unroll
    for (int j=0;j<8;j++){
      unsigned bits = wd[j>>1];
      float xf = (j&1) ? __uint_as_float(bits & 0xffff0000u) : __uint_as_float(bits<<16);
      int c = q*8+j;
      a0 = fmaf(xf, scw[c],       a0);
      a1 = fmaf(xf, scw[224+c],   a1);
      a2 = fmaf(xf, scw[448+c],   a2);
    }
  }
  out_conf[((size_t)(b*3+0))*P_ + p] = sigmoidf_(a0);
  out_conf[((size_t)(b*3+1))*P_ + p] = sigmoidf_(a1);
  out_conf[((size_t)(b*3+2))*P_ + p] = sigmoidf_(a2);
}

// ---------------- 1x1 residual GEMM via MFMA + final mix ----------------
// tile: 64 oc x 256 px (flat over b*P). K=224 in 7 chunks of 32.
__global__ __launch_bounds__(256,4) void k_combine(const unsigned short* __restrict__ ctxb,
    const float* __restrict__ h2, const float* __restrict__ rpw, const float* __restrict__ rpb,
    const float* __restrict__ gatef, const float* __restrict__ conf_out,
    const float* __restrict__ rs, const float* __restrict__ mix, float* __restrict__ dout)
{
  __shared__ short s_x[256*32];   // 16 KB
  __shared__ short s_w[64*32];    // 4 KB
  int t = threadIdx.x;
  size_t p0 = (size_t)blockIdx.x*256;     // flat pixel index over b*P
  int oc0 = blockIdx.y*64, br = blockIdx.y;
  int wv = t>>6, lane = t&63, l15 = lane&15, quad = lane>>4;
  f32x4 acc[4][4];
  #pragma unroll
  for (int mt=0;mt<4;mt++){
    float4 bv = *(const float4*)&rpb[oc0 + mt*16 + quad*4];
    f32x4 iv; iv.x=bv.x; iv.y=bv.y; iv.z=bv.z; iv.w=bv.w;
    #pragma unroll
    for (int nt=0;nt<4;nt++) acc[mt][nt]=iv;
  }
  for (int ch=0; ch<7; ch++){
    int ic0 = ch*32;
    __syncthreads();
    for (int f=t; f<1024; f+=256){
      int icq = f&3, px = f>>2;
      uint4 v = *(const uint4*)&ctxb[(p0+px)*ICP1 + ic0 + icq*8];
      *(uint4*)&s_x[px*32 + ((icq ^ ((px>>1)&3)))*8] = v;
    }
    {
      int oc = t&63, icq = t>>6;
      unsigned short h[8];
      #pragma unroll
      for (int j=0;j<8;j++){
        int ic = ic0 + icq*8 + j;
        h[j] = (ic<194) ? f2bf(rpw[(size_t)(oc0+oc)*194 + ic]) : (unsigned short)0;
      }
      *(uint4*)&s_w[oc*32 + ((icq ^ ((oc>>1)&3)))*8] = *(uint4*)h;
    }
    __syncthreads();
    bf16x8 Af[4], Bf[4];
    #pragma unroll
    for (int mt=0;mt<4;mt++){
      int r = mt*16 + l15;
      Af[mt] = *(const bf16x8*)&s_w[r*32 + (((quad ^ ((r>>1)&3)))&3)*8];
    }
    #pragma unroll
    for (int nt=0;nt<4;nt++){
      int r = wv*64 + nt*16 + l15;
      Bf[nt] = *(const bf16x8*)&s_x[r*32 + (((quad ^ ((r>>1)&3)))&3)*8];
    }
    #pragma unroll
    for (int mt=0;mt<4;mt++)
      #pragma unroll
      for (int nt=0;nt<4;nt++)
        acc[mt][nt] = __builtin_amdgcn_mfma_f32_16x16x32_bf16(Af[mt], Bf[nt], acc[mt][nt], 0, 0, 0);
  }
  float trs = tanhf(rs[0]);
  float ms2 = tanhf(mix[0]);
  int b = (int)(p0 >> 16);
  #pragma unroll
  for (int mt=0;mt<4;mt++){
    int oc = oc0 + mt*16 + quad*4;
    int cc = oc & 63;
    float4 gv = *(const float4*)&gatef[b*192 + oc];
    #pragma unroll
    for (int nt=0;nt<4;nt++){
      size_t pf = p0 + wv*64 + nt*16 + l15;
      int p = (int)(pf & 65535);
      ushort4 fh = *(const ushort4*)&ctxb[pf*ICP1 + oc];
      float4 hv = *(const float4*)&h2[pf*192 + oc];
      float cf = conf_out[((size_t)(b*3+br))*P_ + p];
      size_t dst = (size_t)br*OUT_B + ((size_t)(b*64+cc))*P_ + p;
      dout[dst]            = bf2f(fh.x) + ms2*(hv.x*gv.x + trs*acc[mt][nt].x)*cf;
      dout[dst + P_]       = bf2f(fh.y) + ms2*(hv.y*gv.y + trs*acc[mt][nt].y)*cf;
      dout[dst + 2*P_]     = bf2f(fh.z) + ms2*(hv.z*gv.z + trs*acc[mt][nt].z)*cf;
      dout[dst + 3*P_]     = bf2f(fh.w) + ms2*(hv.w*gv.w + trs*acc[mt][nt].w)*cf;
    }
  }
}

extern "C" void kernel_launch(void* const* d_in, const int* in_sizes, int n_in,
                              void* d_out, int out_size, void* d_ws, size_t ws_size,
                              hipStream_t stream)
{
  const float* vf    = (const float*)d_in[0];
  const float* uvs   = (const float*)d_in[1];
  const float* masks = (const float*)d_in[2];
  const float* wg    = (const float*)d_in[3];
  const float* wb    = (const float*)d_in[4];
  const float* wh    = (const float*)d_in[5];
  const float* c1w = (const float*)d_in[7];
  const float* c1b = (const float*)d_in[8];
  const float* g1s = (const float*)d_in[9];
  const float* g1b = (const float*)d_in[10];
  const float* c2w = (const float*)d_in[11];
  const float* c2b = (const float*)d_in[12];
  const float* g2s = (const float*)d_in[13];
  const float* g2b = (const float*)d_in[14];
  const float* gw1 = (const float*)d_in[15];
  const float* gb1 = (const float*)d_in[16];
  const float* gw2 = (const float*)d_in[17];
  const float* gb2 = (const float*)d_in[18];
  const float* rpw = (const float*)d_in[19];
  const float* rpb = (const float*)d_in[20];
  const float* rs  = (const float*)d_in[21];
  const float* cw  = (const float*)d_in[22];
  const float* cb  = (const float*)d_in[23];
  const float* mix = (const float*)d_in[24];

  char* ws = (char*)d_ws;
  float*          accb  = (float*)(ws + OFF_ACC);
  float*          cntb  = (float*)(ws + OFF_CNT);
  unsigned short* ctxb  = (unsigned short*)(ws + OFF_CTXB);
  unsigned short* h1act = (unsigned short*)(ws + OFF_H1A);
  unsigned short* w1p   = (unsigned short*)(ws + OFF_W1);
  unsigned short* w2p   = (unsigned short*)(ws + OFF_W2);
  float*  h1raw  = (float*)(ws + OFF_ACC);
  float*  h2     = (float*)(ws + OFF_ACC);
  double* stats1 = (double*)(ws + OFF_SM + SM_STATS1);
  double* stats2 = (double*)(ws + OFF_SM + SM_STATS2);
  int*    scale  = (int*)(ws + OFF_SM + SM_SCALE);
  float*  pooled = (float*)(ws + OFF_SM + SM_POOLED);
  float*  gatef  = (float*)(ws + OFF_SM + SM_GATE);
  float*  rawu   = (float*)(ws + OFF_SM + SM_RAWU);

  float* out = (float*)d_out;
  float* out_cov  = out + OUT_COV;
  float* out_unc  = out + OUT_UNC;
  float* out_conf = out + OUT_CONF;

  hipMemsetAsync(ws + OFF_ACC, 0, SZ_ACC + SZ_CNT, stream);
  hipMemsetAsync(ws + OFF_SM, 0, 8192, stream);

  k_prep<<<2808, 256, 0, stream>>>(c1w, c2w, w1p, w2p);
  k_fuse<<<4096, 256, 0, stream>>>(vf, uvs, masks, wg, wb, wh, accb, cntb);
  k_finalize<<<2048, 256, 0, stream>>>(accb, cntb, ctxb, out_cov, rawu, scale);
  k_norm_unc<<<512, 256, 0, stream>>>(ctxb, scale, rawu, out_cov, out_unc);
  k_conv3<ICP1,7><<<dim3(256,3,2), 256, 0, stream>>>(ctxb, w1p, c1b, h1raw);
  k_gn_stats<<<dim3(128,2), 256, 0, stream>>>(h1raw, stats1);
  k_gn1_apply<<<12288, 256, 0, stream>>>(h1raw, stats1, g1s, g1b, h1act);
  k_conv3<ICP2,6><<<dim3(256,3,2), 256, 0, stream>>>(h1act, w2p, c2b, h2);
  k_gn_stats<<<dim3(128,2), 256, 0, stream>>>(h2, stats2);
  k_gn2_apply<<<12288, 256, 0, stream>>>(h2, stats2, g2s, g2b);
  k_pool<<<dim3(64,2), 256, 0, stream>>>(h2, pooled);
  k_gate<<<1, 256, 0, stream>>>(pooled, gw1, gb1, gw2, gb2, gatef);
  k_conf<<<512, 256, 0, stream>>>(ctxb, cw, cb, out_conf);
  k_combine<<<dim3(512,3), 256, 0, stream>>>(ctxb, h2, rpw, rpb, gatef, out_conf, rs, mix, out);
}